// Round 1
// baseline (922.714 us; speedup 1.0000x reference)
//
#include <hip/hip_runtime.h>
#include <hip/hip_bf16.h>

// Sizes (compile-time constants from the reference)
#define BB 512
#define TT 300
#define IN_S 128
#define IN_D 64
#define HS 256
#define HD 128
#define CD 512  // 2*HD + HS

// ---------------------------------------------------------------------------
// Kernel A: static MLP + static part of the per-neuron head dot.
// One block per sample b, 256 threads. ds[b] = s2 . Wg[b,0:256] + fc_b[n]
// ---------------------------------------------------------------------------
__global__ __launch_bounds__(256) void static_head_kernel(
    const float* __restrict__ xs, const int* __restrict__ norder,
    const float* __restrict__ w1, const float* __restrict__ b1,
    const float* __restrict__ w2, const float* __restrict__ b2,
    const float* __restrict__ fcw, const float* __restrict__ fcb,
    float* __restrict__ ds)
{
    __shared__ float xb[IN_S];
    __shared__ float s1[HS];
    __shared__ float red[4];
    const int b = blockIdx.x, tid = threadIdx.x;
    if (tid < IN_S) xb[tid] = xs[(size_t)b * IN_S + tid];
    __syncthreads();

    float a0 = 0.f, a1 = 0.f, a2 = 0.f, a3 = 0.f;
    {
        const float4* wsrc = (const float4*)(w1 + (size_t)tid * IN_S);
        const float4* x4 = (const float4*)xb;
#pragma unroll
        for (int i = 0; i < IN_S / 4; ++i) {
            float4 w = wsrc[i], x = x4[i];
            a0 = fmaf(w.x, x.x, a0); a1 = fmaf(w.y, x.y, a1);
            a2 = fmaf(w.z, x.z, a2); a3 = fmaf(w.w, x.w, a3);
        }
    }
    s1[tid] = fmaxf(b1[tid] + ((a0 + a1) + (a2 + a3)), 0.f);
    __syncthreads();

    a0 = a1 = a2 = a3 = 0.f;
    {
        const float4* wsrc = (const float4*)(w2 + (size_t)tid * HS);
        const float4* x4 = (const float4*)s1;
#pragma unroll
        for (int i = 0; i < HS / 4; ++i) {
            float4 w = wsrc[i], x = x4[i];
            a0 = fmaf(w.x, x.x, a0); a1 = fmaf(w.y, x.y, a1);
            a2 = fmaf(w.z, x.z, a2); a3 = fmaf(w.w, x.w, a3);
        }
    }
    float s2 = fmaxf(b2[tid] + ((a0 + a1) + (a2 + a3)), 0.f);

    const int n = norder[b];
    float p = s2 * fcw[(size_t)n * CD + tid];  // static dims are 0..255 of concat
#pragma unroll
    for (int o = 32; o >= 1; o >>= 1) p += __shfl_down(p, o);
    if ((tid & 63) == 0) red[tid >> 6] = p;
    __syncthreads();
    if (tid == 0) ds[b] = red[0] + red[1] + red[2] + red[3] + fcb[n];
}

// ---------------------------------------------------------------------------
// Kernel B: d = relu(x_dyn @ w_d^T + b_d); pre_f = d @ w_ih_f^T + (b_ih_f+b_hh_f);
//           pre_b = d @ w_ih_b^T + (b_ih_b+b_hh_b).  d stays in LDS.
// 64 rows (b,t pairs) per block, 256 threads. 2400 blocks.
// ---------------------------------------------------------------------------
template <typename PreT>
__global__ __launch_bounds__(256) void proj_pre_kernel(
    const float* __restrict__ xd,
    const float* __restrict__ wd, const float* __restrict__ bd,
    const float* __restrict__ wf, const float* __restrict__ bif, const float* __restrict__ bhf,
    const float* __restrict__ wb, const float* __restrict__ bib, const float* __restrict__ bhb,
    PreT* __restrict__ pre_f, PreT* __restrict__ pre_b)
{
    __shared__ float xt[64 * IN_D];   // 16 KB
    __shared__ float dt[64 * HD];     // 32 KB
    const int tid = threadIdx.x;
    const size_t r0 = (size_t)blockIdx.x * 64;

    {   // stage x tile (coalesced float4)
        const float4* src = (const float4*)(xd + r0 * IN_D);
        float4* dst = (float4*)xt;
#pragma unroll
        for (int i = 0; i < 4; ++i) dst[i * 256 + tid] = src[i * 256 + tid];
    }
    __syncthreads();

    const int j = tid & 127;
    const int g = tid >> 7;

    {   // phase 1: d tile
        float wr[IN_D];
        const float4* wsrc = (const float4*)(wd + (size_t)j * IN_D);
#pragma unroll
        for (int i = 0; i < IN_D / 4; ++i) {
            float4 v = wsrc[i];
            wr[4 * i] = v.x; wr[4 * i + 1] = v.y; wr[4 * i + 2] = v.z; wr[4 * i + 3] = v.w;
        }
        const float bj = bd[j];
        for (int r = g * 32; r < g * 32 + 32; ++r) {
            const float4* xr = (const float4*)(xt + r * IN_D);
            float a0 = 0.f, a1 = 0.f, a2 = 0.f, a3 = 0.f;
#pragma unroll
            for (int i = 0; i < IN_D / 4; ++i) {
                float4 x4 = xr[i];
                a0 = fmaf(wr[4 * i], x4.x, a0); a1 = fmaf(wr[4 * i + 1], x4.y, a1);
                a2 = fmaf(wr[4 * i + 2], x4.z, a2); a3 = fmaf(wr[4 * i + 3], x4.w, a3);
            }
            dt[r * HD + j] = fmaxf(bj + ((a0 + a1) + (a2 + a3)), 0.f);
        }
    }
    __syncthreads();

    {   // phase 2: pre_f (g==0) / pre_b (g==1)
        const float* wih = g ? wb : wf;
        const float bias = g ? (bib[j] + bhb[j]) : (bif[j] + bhf[j]);
        PreT* outp = g ? pre_b : pre_f;
        float wr[HD];
        const float4* wsrc = (const float4*)(wih + (size_t)j * HD);
#pragma unroll
        for (int i = 0; i < HD / 4; ++i) {
            float4 v = wsrc[i];
            wr[4 * i] = v.x; wr[4 * i + 1] = v.y; wr[4 * i + 2] = v.z; wr[4 * i + 3] = v.w;
        }
        for (int r = 0; r < 64; ++r) {
            const float4* dr = (const float4*)(dt + r * HD);
            float a0 = 0.f, a1 = 0.f, a2 = 0.f, a3 = 0.f;
#pragma unroll
            for (int i = 0; i < HD / 4; ++i) {
                float4 d4 = dr[i];
                a0 = fmaf(wr[4 * i], d4.x, a0); a1 = fmaf(wr[4 * i + 1], d4.y, a1);
                a2 = fmaf(wr[4 * i + 2], d4.z, a2); a3 = fmaf(wr[4 * i + 3], d4.w, a3);
            }
            float acc = bias + ((a0 + a1) + (a2 + a3));
            outp[(r0 + r) * HD + j] = (PreT)acc;
        }
    }
}

// ---------------------------------------------------------------------------
// Kernel C: the bidirectional ReLU-RNN + fused head dot for the dynamic part.
// One block per (sample, direction): 1024 blocks, 256 threads.
// Thread (j = tid&127, kg = tid>>7) holds w_hh[j, kg*64 .. kg*64+63] in VGPRs.
// Per step: partial matvec, combine via LDS, relu, dot with gathered head
// weight, wave-reduce, store dot scalar. hf/hb never hit HBM.
// ---------------------------------------------------------------------------
template <typename PreT>
__global__ __launch_bounds__(256) void rnn_kernel(
    const PreT* __restrict__ pre_f, const PreT* __restrict__ pre_b,
    const float* __restrict__ whh_f, const float* __restrict__ whh_b,
    const float* __restrict__ fcw, const int* __restrict__ norder,
    float* __restrict__ dotf, float* __restrict__ dotb)
{
    const int bid = blockIdx.x;
    const int dir = bid >> 9;       // 0 = forward, 1 = backward
    const int s = bid & 511;
    const PreT* pre = (dir ? pre_b : pre_f) + (size_t)s * TT * HD;
    const float* whh = dir ? whh_b : whh_f;
    float* dout = (dir ? dotb : dotf) + (size_t)s * TT;

    const int tid = threadIdx.x;
    const int j = tid & 127, kg = tid >> 7;

    float wr[64];
    {
        const float4* wsrc = (const float4*)(whh + (size_t)j * HD + kg * 64);
#pragma unroll
        for (int i = 0; i < 16; ++i) {
            float4 v = wsrc[i];
            wr[4 * i] = v.x; wr[4 * i + 1] = v.y; wr[4 * i + 2] = v.z; wr[4 * i + 3] = v.w;
        }
    }
    const int n = norder[s];
    const float wg = fcw[(size_t)n * CD + (dir ? (HS + HD) : HS) + j];

    __shared__ float hS[HD];
    __shared__ float pS[HD];
    __shared__ float red[2];
    if (tid < HD) hS[tid] = 0.f;
    __syncthreads();

    int t = dir ? (TT - 1) : 0;
    const int dstep = dir ? -1 : 1;
    float pnext = (kg == 0) ? (float)pre[t * HD + j] : 0.f;

    for (int step = 0; step < TT; ++step) {
        // partial = sum over this thread's k-range of w_hh[j,k] * h[k]
        float a0 = 0.f, a1 = 0.f, a2 = 0.f, a3 = 0.f;
        const float4* h4 = ((const float4*)hS) + kg * 16;
#pragma unroll
        for (int i = 0; i < 16; ++i) {
            float4 h = h4[i];
            a0 = fmaf(wr[4 * i], h.x, a0); a1 = fmaf(wr[4 * i + 1], h.y, a1);
            a2 = fmaf(wr[4 * i + 2], h.z, a2); a3 = fmaf(wr[4 * i + 3], h.w, a3);
        }
        float part = (a0 + a1) + (a2 + a3);
        float pcur = pnext;
        if (kg == 1) pS[j] = part;
        __syncthreads();
        // prefetch next timestep's pre row (latency hides under reduce+barrier)
        if (step + 1 < TT && kg == 0) pnext = (float)pre[(t + dstep) * HD + j];

        float hw = 0.f;
        if (kg == 0) {
            float hnew = fmaxf(pcur + part + pS[j], 0.f);
            hS[j] = hnew;
            hw = hnew * wg;
        }
#pragma unroll
        for (int o = 32; o >= 1; o >>= 1) hw += __shfl_down(hw, o);
        if (kg == 0 && (tid & 63) == 0) red[tid >> 6] = hw;
        __syncthreads();
        if (tid == 0) dout[t] = red[0] + red[1];
        t += dstep;
    }
}

// ---------------------------------------------------------------------------
// Kernel D: out[b,t] = relu(ds[b] + dotf[b,t] + dotb[b,t])
// ---------------------------------------------------------------------------
__global__ __launch_bounds__(256) void final_kernel(
    const float* __restrict__ ds, const float* __restrict__ dotf,
    const float* __restrict__ dotb, float* __restrict__ out)
{
    const int idx = blockIdx.x * 256 + threadIdx.x;  // < 153600 exactly
    const int b = idx / TT;
    out[idx] = fmaxf(ds[b] + dotf[idx] + dotb[idx], 0.f);
}

// ---------------------------------------------------------------------------
extern "C" void kernel_launch(void* const* d_in, const int* in_sizes, int n_in,
                              void* d_out, int out_size, void* d_ws, size_t ws_size,
                              hipStream_t stream)
{
    const float* x_static = (const float*)d_in[0];
    const float* x_dyn    = (const float*)d_in[1];
    const int*   norder   = (const int*)d_in[2];
    const float* w_s1 = (const float*)d_in[3];  const float* b_s1 = (const float*)d_in[4];
    const float* w_s2 = (const float*)d_in[5];  const float* b_s2 = (const float*)d_in[6];
    const float* w_d  = (const float*)d_in[7];  const float* b_d  = (const float*)d_in[8];
    const float* w_ih_f = (const float*)d_in[9];  const float* w_hh_f = (const float*)d_in[10];
    const float* b_ih_f = (const float*)d_in[11]; const float* b_hh_f = (const float*)d_in[12];
    const float* w_ih_b = (const float*)d_in[13]; const float* w_hh_b = (const float*)d_in[14];
    const float* b_ih_b = (const float*)d_in[15]; const float* b_hh_b = (const float*)d_in[16];
    const float* fc_w = (const float*)d_in[17];  const float* fc_b = (const float*)d_in[18];
    float* out = (float*)d_out;

    const size_t preE = (size_t)BB * TT * HD;          // 19,660,800 elems per buffer
    const size_t dotE = (size_t)BB * TT;               // 153,600
    const size_t need_f32 = preE * 2 * sizeof(float) + dotE * 2 * sizeof(float) + BB * sizeof(float);
    const bool f32pre = (ws_size >= need_f32);

    char* p = (char*)d_ws;
    void* pre_f_v = p;
    void* pre_b_v;
    float *dotf, *dotb, *ds;
    if (f32pre) {
        pre_b_v = p + preE * sizeof(float);
        dotf = (float*)(p + preE * 2 * sizeof(float));
    } else {
        pre_b_v = p + preE * sizeof(__hip_bfloat16);
        dotf = (float*)(p + preE * 2 * sizeof(__hip_bfloat16));
    }
    dotb = dotf + dotE;
    ds = dotb + dotE;

    // A: static MLP + static head dot (independent of B/C)
    static_head_kernel<<<BB, 256, 0, stream>>>(x_static, norder, w_s1, b_s1, w_s2, b_s2,
                                               fc_w, fc_b, ds);
    if (f32pre) {
        proj_pre_kernel<float><<<(BB * TT) / 64, 256, 0, stream>>>(
            x_dyn, w_d, b_d, w_ih_f, b_ih_f, b_hh_f, w_ih_b, b_ih_b, b_hh_b,
            (float*)pre_f_v, (float*)pre_b_v);
        rnn_kernel<float><<<BB * 2, 256, 0, stream>>>(
            (const float*)pre_f_v, (const float*)pre_b_v, w_hh_f, w_hh_b,
            fc_w, norder, dotf, dotb);
    } else {
        proj_pre_kernel<__hip_bfloat16><<<(BB * TT) / 64, 256, 0, stream>>>(
            x_dyn, w_d, b_d, w_ih_f, b_ih_f, b_hh_f, w_ih_b, b_ih_b, b_hh_b,
            (__hip_bfloat16*)pre_f_v, (__hip_bfloat16*)pre_b_v);
        rnn_kernel<__hip_bfloat16><<<BB * 2, 256, 0, stream>>>(
            (const __hip_bfloat16*)pre_f_v, (const __hip_bfloat16*)pre_b_v, w_hh_f, w_hh_b,
            fc_w, norder, dotf, dotb);
    }
    final_kernel<<<(BB * TT) / 256, 256, 0, stream>>>(ds, dotf, dotb, out);
}

// Round 2
// 284.822 us; speedup vs baseline: 3.2396x; 3.2396x over previous
//
#include <hip/hip_runtime.h>
#include <hip/hip_bf16.h>

#define BB 512
#define TT 300
#define IN_S 128
#define IN_D 64
#define HS 256
#define HD 128
#define CD 512  // 2*HD + HS

typedef __attribute__((ext_vector_type(8))) short bf16x8;
typedef __attribute__((ext_vector_type(4))) float f32x4;
typedef unsigned short ushort_t;

static __device__ __forceinline__ ushort_t f2bf(float x) {
    unsigned u = __builtin_bit_cast(unsigned, x);
    unsigned r = (u + 0x7FFFu + ((u >> 16) & 1u)) >> 16;  // RNE
    return (ushort_t)r;
}
static __device__ __forceinline__ float bf2f(ushort_t h) {
    unsigned u = ((unsigned)h) << 16;
    return __builtin_bit_cast(float, u);
}

// ---------------------------------------------------------------------------
// prep: f32 weights -> bf16 workspace copies; fused RNN bias sums.
// 64 blocks x 256 = 16384 threads.
// ---------------------------------------------------------------------------
__global__ __launch_bounds__(256) void prep_kernel(
    const float* __restrict__ wd, const float* __restrict__ wihf, const float* __restrict__ wihb,
    const float* __restrict__ whhf, const float* __restrict__ whhb,
    const float* __restrict__ bif, const float* __restrict__ bhf,
    const float* __restrict__ bib, const float* __restrict__ bhb,
    ushort_t* __restrict__ wd_bf, ushort_t* __restrict__ wihf_bf, ushort_t* __restrict__ wihb_bf,
    ushort_t* __restrict__ whhf_bf, ushort_t* __restrict__ whhb_bf,
    float* __restrict__ bsf, float* __restrict__ bsb)
{
    const int i = blockIdx.x * 256 + threadIdx.x;  // < 16384
    if (i < HD * IN_D) wd_bf[i] = f2bf(wd[i]);
    wihf_bf[i] = f2bf(wihf[i]);
    wihb_bf[i] = f2bf(wihb[i]);
    whhf_bf[i] = f2bf(whhf[i]);
    whhb_bf[i] = f2bf(whhb[i]);
    if (i < HD) { bsf[i] = bif[i] + bhf[i]; bsb[i] = bib[i] + bhb[i]; }
}

// ---------------------------------------------------------------------------
// Kernel A (unchanged from round 0, validated): static MLP + static head dot.
// ---------------------------------------------------------------------------
__global__ __launch_bounds__(256) void static_head_kernel(
    const float* __restrict__ xs, const int* __restrict__ norder,
    const float* __restrict__ w1, const float* __restrict__ b1,
    const float* __restrict__ w2, const float* __restrict__ b2,
    const float* __restrict__ fcw, const float* __restrict__ fcb,
    float* __restrict__ ds)
{
    __shared__ float xb[IN_S];
    __shared__ float s1[HS];
    __shared__ float red[4];
    const int b = blockIdx.x, tid = threadIdx.x;
    if (tid < IN_S) xb[tid] = xs[(size_t)b * IN_S + tid];
    __syncthreads();

    float a0 = 0.f, a1 = 0.f, a2 = 0.f, a3 = 0.f;
    {
        const float4* wsrc = (const float4*)(w1 + (size_t)tid * IN_S);
        const float4* x4 = (const float4*)xb;
#pragma unroll
        for (int i = 0; i < IN_S / 4; ++i) {
            float4 w = wsrc[i], x = x4[i];
            a0 = fmaf(w.x, x.x, a0); a1 = fmaf(w.y, x.y, a1);
            a2 = fmaf(w.z, x.z, a2); a3 = fmaf(w.w, x.w, a3);
        }
    }
    s1[tid] = fmaxf(b1[tid] + ((a0 + a1) + (a2 + a3)), 0.f);
    __syncthreads();

    a0 = a1 = a2 = a3 = 0.f;
    {
        const float4* wsrc = (const float4*)(w2 + (size_t)tid * HS);
        const float4* x4 = (const float4*)s1;
#pragma unroll
        for (int i = 0; i < HS / 4; ++i) {
            float4 w = wsrc[i], x = x4[i];
            a0 = fmaf(w.x, x.x, a0); a1 = fmaf(w.y, x.y, a1);
            a2 = fmaf(w.z, x.z, a2); a3 = fmaf(w.w, x.w, a3);
        }
    }
    float s2 = fmaxf(b2[tid] + ((a0 + a1) + (a2 + a3)), 0.f);

    const int n = norder[b];
    float p = s2 * fcw[(size_t)n * CD + tid];
#pragma unroll
    for (int o = 32; o >= 1; o >>= 1) p += __shfl_down(p, o);
    if ((tid & 63) == 0) red[tid >> 6] = p;
    __syncthreads();
    if (tid == 0) ds[b] = red[0] + red[1] + red[2] + red[3] + fcb[n];
}

// ---------------------------------------------------------------------------
// proj: MFMA bf16. Block = 128 rows of x_dyn (m = b*T+t), 4 waves.
//  phase1: d = relu(x @ wd^T + bd)   -> d in LDS (bf16, XOR-swizzled rows)
//  phase2: pre_{f,b} = d @ wih^T + bsum -> global bf16 in [t][s][j] layout
// Wave w owns rows (w*32..w*32+32), all 128 cols.
// ---------------------------------------------------------------------------
__global__ __launch_bounds__(256) void proj_kernel(
    const float* __restrict__ xd, const ushort_t* __restrict__ wd_bf,
    const float* __restrict__ bd,
    const ushort_t* __restrict__ wihf_bf, const ushort_t* __restrict__ wihb_bf,
    const float* __restrict__ bsf, const float* __restrict__ bsb,
    ushort_t* __restrict__ preF, ushort_t* __restrict__ preB)
{
    __shared__ char lds[49152];  // [0,32768): d tile [128][128]bf16; [32768,49152): x tile [128][64]bf16
    char* dbase = lds;
    char* xbase = lds + 32768;
    const int tid = threadIdx.x;
    const int m0 = blockIdx.x * 128;

    {   // stage x -> bf16 LDS (swizzled). thread: row tid>>1, half tid&1 (32 floats)
        const int row = tid >> 1, half = tid & 1;
        const int swz = (row & 7) << 4;
        const float4* src = (const float4*)(xd + (size_t)(m0 + row) * IN_D + half * 32);
#pragma unroll
        for (int i = 0; i < 4; ++i) {
            float4 a = src[2 * i], b = src[2 * i + 1];
            bf16x8 v;
            v[0] = (short)f2bf(a.x); v[1] = (short)f2bf(a.y);
            v[2] = (short)f2bf(a.z); v[3] = (short)f2bf(a.w);
            v[4] = (short)f2bf(b.x); v[5] = (short)f2bf(b.y);
            v[6] = (short)f2bf(b.z); v[7] = (short)f2bf(b.w);
            *(bf16x8*)(xbase + ((row * 128 + half * 64 + i * 16) ^ swz)) = v;
        }
    }
    __syncthreads();

    const int w = tid >> 6, l = tid & 63;
    const int lr = l & 15, lg = l >> 4;

    // ---- phase 1 ----
    f32x4 acc[2][8];
#pragma unroll
    for (int mt = 0; mt < 2; ++mt)
#pragma unroll
        for (int nt = 0; nt < 8; ++nt) acc[mt][nt] = (f32x4){0.f, 0.f, 0.f, 0.f};

    for (int kk = 0; kk < 2; ++kk) {
        bf16x8 a[2], b[8];
#pragma unroll
        for (int mt = 0; mt < 2; ++mt) {
            const int row = (w * 2 + mt) * 16 + lr;
            a[mt] = *(const bf16x8*)(xbase + ((row * 128 + kk * 64 + lg * 16) ^ ((row & 7) << 4)));
        }
#pragma unroll
        for (int nt = 0; nt < 8; ++nt)
            b[nt] = *(const bf16x8*)(wd_bf + (nt * 16 + lr) * IN_D + kk * 32 + lg * 8);
#pragma unroll
        for (int mt = 0; mt < 2; ++mt)
#pragma unroll
            for (int nt = 0; nt < 8; ++nt)
                acc[mt][nt] = __builtin_amdgcn_mfma_f32_16x16x32_bf16(a[mt], b[nt], acc[mt][nt], 0, 0, 0);
    }
    // epilogue 1: relu(+bd) -> d LDS (swizzled b16 writes)
#pragma unroll
    for (int nt = 0; nt < 8; ++nt) {
        const float bj = bd[nt * 16 + lr];
        const int col2 = (nt * 16 + lr) * 2;
#pragma unroll
        for (int mt = 0; mt < 2; ++mt)
#pragma unroll
            for (int r = 0; r < 4; ++r) {
                const int row = (w * 2 + mt) * 16 + lg * 4 + r;
                const float v = fmaxf(acc[mt][nt][r] + bj, 0.f);
                *(ushort_t*)(dbase + ((row * 256 + col2) ^ ((row & 7) << 4))) = f2bf(v);
            }
    }
    __syncthreads();

    // ---- phase 2: two output matrices ----
#pragma unroll
    for (int mat = 0; mat < 2; ++mat) {
        const ushort_t* wm = mat ? wihb_bf : wihf_bf;
        const float* bs = mat ? bsb : bsf;
        ushort_t* outp = mat ? preB : preF;

        f32x4 acc2[2][8];
#pragma unroll
        for (int mt = 0; mt < 2; ++mt)
#pragma unroll
            for (int nt = 0; nt < 8; ++nt) acc2[mt][nt] = (f32x4){0.f, 0.f, 0.f, 0.f};

        for (int kk = 0; kk < 4; ++kk) {
            bf16x8 a[2], b[8];
#pragma unroll
            for (int mt = 0; mt < 2; ++mt) {
                const int row = (w * 2 + mt) * 16 + lr;
                a[mt] = *(const bf16x8*)(dbase + ((row * 256 + kk * 64 + lg * 16) ^ ((row & 7) << 4)));
            }
#pragma unroll
            for (int nt = 0; nt < 8; ++nt)
                b[nt] = *(const bf16x8*)(wm + (nt * 16 + lr) * HD + kk * 32 + lg * 8);
#pragma unroll
            for (int mt = 0; mt < 2; ++mt)
#pragma unroll
                for (int nt = 0; nt < 8; ++nt)
                    acc2[mt][nt] = __builtin_amdgcn_mfma_f32_16x16x32_bf16(a[mt], b[nt], acc2[mt][nt], 0, 0, 0);
        }
        // epilogue: + bias, cvt, scatter to [t][s][j]
        float bsv[8];
#pragma unroll
        for (int nt = 0; nt < 8; ++nt) bsv[nt] = bs[nt * 16 + lr];
#pragma unroll
        for (int mt = 0; mt < 2; ++mt)
#pragma unroll
            for (int r = 0; r < 4; ++r) {
                const unsigned m = (unsigned)(m0 + (w * 2 + mt) * 16 + lg * 4 + r);
                const unsigned s = m / TT, t = m % TT;  // compiler magic-div
                ushort_t* rowp = outp + ((size_t)t * BB + s) * HD;
#pragma unroll
                for (int nt = 0; nt < 8; ++nt)
                    rowp[nt * 16 + lr] = f2bf(acc2[mt][nt][r] + bsv[nt]);
            }
    }
}

// ---------------------------------------------------------------------------
// rnn: MFMA recurrence. 64 blocks = 32 sample-groups x 2 dirs, 256 threads.
// M=16 samples; wave w owns output cols [w*32, w*32+32). w_hh lives in
// B-fragments (VGPRs) for all 300 steps. h double-buffered in swizzled LDS.
// pre read 1 step ahead into regs; h (bf16) written back OVER pre[t] (aliased).
// ---------------------------------------------------------------------------
__global__ __launch_bounds__(256) void rnn_kernel(
    ushort_t* __restrict__ preF, ushort_t* __restrict__ preB,
    const ushort_t* __restrict__ whhF_bf, const ushort_t* __restrict__ whhB_bf)
{
    __shared__ char hlds[8192];  // 2 x [16][128] bf16, swizzled
    const int bid = blockIdx.x;
    const int dir = bid & 1;
    const int s0 = (bid >> 1) * 16;
    ushort_t* pre = dir ? preB : preF;
    const ushort_t* whh = dir ? whhB_bf : whhF_bf;

    const int tid = threadIdx.x;
    const int w = tid >> 6, l = tid & 63;
    const int lr = l & 15, lg = l >> 4;

    bf16x8 B[2][4];
#pragma unroll
    for (int n2 = 0; n2 < 2; ++n2)
#pragma unroll
        for (int kk = 0; kk < 4; ++kk)
            B[n2][kk] = *(const bf16x8*)(whh + ((w * 2 + n2) * 16 + lr) * HD + kk * 32 + lg * 8);

    ((float4*)hlds)[tid] = (float4){0.f, 0.f, 0.f, 0.f};  // zero buffer 0 (4096 B)

    int t = dir ? (TT - 1) : 0;
    const int dt = dir ? -1 : 1;

    // prefetch pre[t0]
    ushort_t pv[8];
#pragma unroll
    for (int n2 = 0; n2 < 2; ++n2)
#pragma unroll
        for (int r = 0; r < 4; ++r)
            pv[n2 * 4 + r] = pre[((size_t)t * BB + (s0 + lg * 4 + r)) * HD + (w * 2 + n2) * 16 + lr];
    __syncthreads();

    int cur = 0;
    for (int step = 0; step < TT; ++step, t += dt) {
        bf16x8 A[4];
#pragma unroll
        for (int kk = 0; kk < 4; ++kk)
            A[kk] = *(const bf16x8*)(hlds + cur * 4096 + ((lr * 256 + kk * 64 + lg * 16) ^ ((lr & 7) << 4)));

        f32x4 acc[2];
        acc[0] = (f32x4){0.f, 0.f, 0.f, 0.f};
        acc[1] = (f32x4){0.f, 0.f, 0.f, 0.f};
#pragma unroll
        for (int kk = 0; kk < 4; ++kk) {
            acc[0] = __builtin_amdgcn_mfma_f32_16x16x32_bf16(A[kk], B[0][kk], acc[0], 0, 0, 0);
            acc[1] = __builtin_amdgcn_mfma_f32_16x16x32_bf16(A[kk], B[1][kk], acc[1], 0, 0, 0);
        }

        const int tn = t + dt;
        const bool havenext = (step + 1 < TT);
        ushort_t pnew[8];
#pragma unroll
        for (int n2 = 0; n2 < 2; ++n2)
#pragma unroll
            for (int r = 0; r < 4; ++r) {
                const int idx = n2 * 4 + r;
                const float v = fmaxf(acc[n2][r] + bf2f(pv[idx]), 0.f);
                const ushort_t hb = f2bf(v);
                const int row = lg * 4 + r;
                const int col = (w * 2 + n2) * 16 + lr;
                *(ushort_t*)(hlds + (cur ^ 1) * 4096 + ((row * 256 + col * 2) ^ ((row & 7) << 4))) = hb;
                const size_t sc = (size_t)(s0 + row) * HD + col;
                pre[(size_t)t * (BB * HD) + sc] = hb;  // h out, in-place over consumed pre
                if (havenext) pnew[idx] = pre[(size_t)tn * (BB * HD) + sc];
            }
#pragma unroll
        for (int i = 0; i < 8; ++i) pv[i] = pnew[i];
        __syncthreads();
        cur ^= 1;
    }
}

// ---------------------------------------------------------------------------
// dot: out[s,t] = relu(ds[s] + hf[t,s,:].wgf + hb[t,s,:].wgb)
// Wave = (sample s, 60-t chunk); lane: lg = t within quad, lr = 8-elem j slice.
// ---------------------------------------------------------------------------
__global__ __launch_bounds__(256) void dot_kernel(
    const ushort_t* __restrict__ hF, const ushort_t* __restrict__ hB,
    const float* __restrict__ fcw, const int* __restrict__ norder,
    const float* __restrict__ ds, float* __restrict__ out)
{
    const int gw = blockIdx.x * 4 + (threadIdx.x >> 6);  // < 2560
    const int s = gw / 5, chunk = gw % 5;
    const int l = threadIdx.x & 63, lr = l & 15, lg = l >> 4;
    const int n = norder[s];
    const float4* wf4 = (const float4*)(fcw + (size_t)n * CD + HS);
    const float4* wb4 = (const float4*)(fcw + (size_t)n * CD + HS + HD);
    const float4 wf0 = wf4[lr * 2], wf1 = wf4[lr * 2 + 1];
    const float4 wb0 = wb4[lr * 2], wb1 = wb4[lr * 2 + 1];
    const float dsv = ds[s];

    for (int it = 0; it < 15; ++it) {
        const int t = chunk * 60 + it * 4 + lg;
        const size_t off = ((size_t)t * BB + s) * HD + lr * 8;
        const bf16x8 hf = *(const bf16x8*)(hF + off);
        const bf16x8 hb = *(const bf16x8*)(hB + off);
        float a = 0.f;
        a = fmaf(bf2f((ushort_t)hf[0]), wf0.x, a); a = fmaf(bf2f((ushort_t)hf[1]), wf0.y, a);
        a = fmaf(bf2f((ushort_t)hf[2]), wf0.z, a); a = fmaf(bf2f((ushort_t)hf[3]), wf0.w, a);
        a = fmaf(bf2f((ushort_t)hf[4]), wf1.x, a); a = fmaf(bf2f((ushort_t)hf[5]), wf1.y, a);
        a = fmaf(bf2f((ushort_t)hf[6]), wf1.z, a); a = fmaf(bf2f((ushort_t)hf[7]), wf1.w, a);
        a = fmaf(bf2f((ushort_t)hb[0]), wb0.x, a); a = fmaf(bf2f((ushort_t)hb[1]), wb0.y, a);
        a = fmaf(bf2f((ushort_t)hb[2]), wb0.z, a); a = fmaf(bf2f((ushort_t)hb[3]), wb0.w, a);
        a = fmaf(bf2f((ushort_t)hb[4]), wb1.x, a); a = fmaf(bf2f((ushort_t)hb[5]), wb1.y, a);
        a = fmaf(bf2f((ushort_t)hb[6]), wb1.z, a); a = fmaf(bf2f((ushort_t)hb[7]), wb1.w, a);
#pragma unroll
        for (int o = 1; o < 16; o <<= 1) a += __shfl_xor(a, o);
        if (lr == 0) out[s * TT + t] = fmaxf(a + dsv, 0.f);
    }
}

// ---------------------------------------------------------------------------
extern "C" void kernel_launch(void* const* d_in, const int* in_sizes, int n_in,
                              void* d_out, int out_size, void* d_ws, size_t ws_size,
                              hipStream_t stream)
{
    const float* x_static = (const float*)d_in[0];
    const float* x_dyn    = (const float*)d_in[1];
    const int*   norder   = (const int*)d_in[2];
    const float* w_s1 = (const float*)d_in[3];  const float* b_s1 = (const float*)d_in[4];
    const float* w_s2 = (const float*)d_in[5];  const float* b_s2 = (const float*)d_in[6];
    const float* w_d  = (const float*)d_in[7];  const float* b_d  = (const float*)d_in[8];
    const float* w_ih_f = (const float*)d_in[9];  const float* w_hh_f = (const float*)d_in[10];
    const float* b_ih_f = (const float*)d_in[11]; const float* b_hh_f = (const float*)d_in[12];
    const float* w_ih_b = (const float*)d_in[13]; const float* w_hh_b = (const float*)d_in[14];
    const float* b_ih_b = (const float*)d_in[15]; const float* b_hh_b = (const float*)d_in[16];
    const float* fc_w = (const float*)d_in[17];  const float* fc_b = (const float*)d_in[18];
    float* out = (float*)d_out;

    const size_t PRE_BYTES = (size_t)BB * TT * HD * sizeof(ushort_t);  // 39,321,600
    char* p = (char*)d_ws;
    ushort_t* preF    = (ushort_t*)p;
    ushort_t* preB    = (ushort_t*)(p + PRE_BYTES);
    char* q = p + 2 * PRE_BYTES;
    ushort_t* wd_bf   = (ushort_t*)q;               q += 16384 * sizeof(ushort_t); // 8192 elems, padded
    ushort_t* wihf_bf = (ushort_t*)q;               q += 16384 * sizeof(ushort_t);
    ushort_t* wihb_bf = (ushort_t*)q;               q += 16384 * sizeof(ushort_t);
    ushort_t* whhf_bf = (ushort_t*)q;               q += 16384 * sizeof(ushort_t);
    ushort_t* whhb_bf = (ushort_t*)q;               q += 16384 * sizeof(ushort_t);
    float* bsf = (float*)q;                         q += 256 * sizeof(float);
    float* bsb = (float*)q;                         q += 256 * sizeof(float);
    float* ds  = (float*)q;

    prep_kernel<<<64, 256, 0, stream>>>(w_d, w_ih_f, w_ih_b, w_hh_f, w_hh_b,
                                        b_ih_f, b_hh_f, b_ih_b, b_hh_b,
                                        wd_bf, wihf_bf, wihb_bf, whhf_bf, whhb_bf, bsf, bsb);
    static_head_kernel<<<BB, 256, 0, stream>>>(x_static, norder, w_s1, b_s1, w_s2, b_s2,
                                               fc_w, fc_b, ds);
    proj_kernel<<<(BB * TT) / 128, 256, 0, stream>>>(x_dyn, wd_bf, b_d, wihf_bf, wihb_bf,
                                                     bsf, bsb, preF, preB);
    rnn_kernel<<<64, 256, 0, stream>>>(preF, preB, whhf_bf, whhb_bf);
    dot_kernel<<<640, 256, 0, stream>>>(preF, preB, fc_w, norder, ds, out);
}